// Round 5
// baseline (464.065 us; speedup 1.0000x reference)
//
#include <hip/hip_runtime.h>

// Problem constants (match reference)
#define N_NODES 10000
#define N_EDGES 160000
#define DIM_IN 32
#define DIM_OUT 64
#define DIM_HID 128
#define BOND 13
#define NB 4  // source nodes per workgroup (one per wave)

typedef _Float16 half2_t __attribute__((ext_vector_type(2)));
typedef unsigned int uint;
typedef unsigned short ushort;

static __device__ __forceinline__ float fdot2u(uint a, uint b, float c) {
#if __has_builtin(__builtin_amdgcn_fdot2)
    return __builtin_amdgcn_fdot2(__builtin_bit_cast(half2_t, a),
                                  __builtin_bit_cast(half2_t, b), c, false);
#else
    half2_t ha = __builtin_bit_cast(half2_t, a);
    half2_t hb = __builtin_bit_cast(half2_t, b);
    return c + (float)ha.x * (float)hb.x + (float)ha.y * (float)hb.y;
#endif
}

static __device__ __forceinline__ uint packh2(float a, float b) {
    half2_t h;
    h.x = (_Float16)a; h.y = (_Float16)b;
    return __builtin_bit_cast(uint, h);
}

// ======================= shared helpers =======================

// W2 f32 [k][i*64+o] -> f16x2 i-paired W2p[(ip*64+o)*128 + k]
static __device__ __forceinline__ void pack_w2(int idx, const float* W2, uint* W2p) {
    int ip = idx >> 13;
    int o  = (idx >> 7) & 63;
    int k  = idx & 127;
    float lo = W2[k * 2048 + (2 * ip) * 64 + o];
    float hi = W2[k * 2048 + (2 * ip + 1) * 64 + o];
    W2p[idx] = packh2(lo, hi);
}

// single-block exclusive scan of counts->offsets, duplicate into cursor
static __device__ __forceinline__ void scan_one(int* counts, int* cursor, int* s) {
    const int t = threadIdx.x;
    const int base = t * 10;  // 1024*10 >= 10000
    int loc[10];
    int sum = 0;
#pragma unroll
    for (int u = 0; u < 10; ++u) {
        int idx = base + u;
        int v = (idx < N_NODES) ? counts[idx] : 0;
        loc[u] = v; sum += v;
    }
    s[t] = sum;
    __syncthreads();
    for (int off = 1; off < 1024; off <<= 1) {
        int add = (t >= off) ? s[t - off] : 0;
        __syncthreads();
        s[t] += add;
        __syncthreads();
    }
    int run = s[t] - sum;
#pragma unroll
    for (int u = 0; u < 10; ++u) {
        int idx = base + u;
        if (idx < N_NODES) { counts[idx] = run; cursor[idx] = run; }
        run += loc[u];
    }
}

// per-wave edge scratch, overlaid on this wave's 16 KB Ph slot after preg load
struct EScr {
    int   eids[64];
    int   dsts[64];     // dst node (atomic path) OR dst slot position (2-phase)
    float eas[8][16];   // 16B-aligned rows
    uint  hbuf[8][64];  // 16B aligned for uint4 reads
};

// ======================= two-phase path =======================

__global__ void prep2_kernel(const float* __restrict__ W2, uint* __restrict__ W2p,
                             int* __restrict__ csrc, int* __restrict__ cdst) {
    int idx = blockIdx.x * 256 + threadIdx.x;  // grid 512 blocks -> 131072
    if (idx < 16 * 64 * DIM_HID) pack_w2(idx, W2, W2p);
    if (idx < N_NODES) { csrc[idx] = 0; cdst[idx] = 0; }
}

__global__ void hist2_kernel(const int* __restrict__ ei, int* __restrict__ csrc,
                             int* __restrict__ cdst) {
    int e = blockIdx.x * 256 + threadIdx.x;
    if (e < N_EDGES) {
        atomicAdd(&csrc[ei[e]], 1);
        atomicAdd(&cdst[ei[N_EDGES + e]], 1);
    }
}

__global__ void scan2_kernel(int* __restrict__ csrc, int* __restrict__ cur_s,
                             int* __restrict__ cdst, int* __restrict__ cur_d) {
    __shared__ int s[1024];
    scan_one(csrc, cur_s, s);
    __syncthreads();
    scan_one(cdst, cur_d, s);
}

__global__ void scatter2_kernel(const int* __restrict__ ei, int* __restrict__ cur_s,
                                int* __restrict__ cur_d, int* __restrict__ es,
                                int* __restrict__ epos) {
    int e = blockIdx.x * 256 + threadIdx.x;
    if (e < N_EDGES) {
        int ps = atomicAdd(&cur_s[ei[e]], 1);
        es[ps] = e;
        int pd = atomicAdd(&cur_d[ei[N_EDGES + e]], 1);
        epos[e] = pd;
    }
}

// phase 1: P build -> register P -> tiled edge phase -> f16 msg store (no atomics)
__global__ __launch_bounds__(256) void phase1_kernel(
    const float* __restrict__ x, const float* __restrict__ ea,
    const float* __restrict__ W1, const float* __restrict__ b1,
    const uint* __restrict__ W2p, const float* __restrict__ b2,
    const int* __restrict__ offsets, const int* __restrict__ cursor,
    const int* __restrict__ es, const int* __restrict__ epos,
    ushort* __restrict__ msgbuf)
{
    __shared__ uint  Ph[NB][DIM_HID / 2][DIM_OUT];  // 64 KiB, reused as EScr later
    __shared__ float xs_t[DIM_IN][NB];
    __shared__ uint  xsp[DIM_IN / 2][NB];

    const int t  = threadIdx.x;
    const int o  = t & 63;
    const int w  = t >> 6;
    const int n0 = blockIdx.x * NB;

    if (t < DIM_IN * NB) {
        int i = t >> 2, j = t & 3;
        xs_t[i][j] = x[(n0 + j) * DIM_IN + i];
    }
    __syncthreads();
    if (t < (DIM_IN / 2) * NB) {
        int ip = t >> 2, j = t & 3;
        xsp[ip][j] = packh2(xs_t[2 * ip][j], xs_t[2 * ip + 1][j]);
    }
    __syncthreads();

#pragma unroll
    for (int s = 0; s < 4; ++s) {
        const int kbase = w * 32 + s * 8;
        float acc[NB][8];
#pragma unroll
        for (int j = 0; j < NB; ++j)
#pragma unroll
            for (int q = 0; q < 8; ++q) acc[j][q] = 0.f;
#pragma unroll
        for (int ip = 0; ip < 16; ++ip) {
            const uint4* p4 = (const uint4*)(W2p + (ip * 64 + o) * DIM_HID + kbase);
            uint4 wa = p4[0];
            uint4 wb = p4[1];
            uint xp0 = xsp[ip][0], xp1 = xsp[ip][1];
            uint xp2 = xsp[ip][2], xp3 = xsp[ip][3];
#define DO_NODE(j, xp) \
            acc[j][0] = fdot2u(xp, wa.x, acc[j][0]); \
            acc[j][1] = fdot2u(xp, wa.y, acc[j][1]); \
            acc[j][2] = fdot2u(xp, wa.z, acc[j][2]); \
            acc[j][3] = fdot2u(xp, wa.w, acc[j][3]); \
            acc[j][4] = fdot2u(xp, wb.x, acc[j][4]); \
            acc[j][5] = fdot2u(xp, wb.y, acc[j][5]); \
            acc[j][6] = fdot2u(xp, wb.z, acc[j][6]); \
            acc[j][7] = fdot2u(xp, wb.w, acc[j][7]);
            DO_NODE(0, xp0) DO_NODE(1, xp1) DO_NODE(2, xp2) DO_NODE(3, xp3)
#undef DO_NODE
        }
#pragma unroll
        for (int j = 0; j < NB; ++j)
#pragma unroll
            for (int q2 = 0; q2 < 4; ++q2)
                Ph[j][kbase / 2 + q2][o] = packh2(acc[j][2 * q2], acc[j][2 * q2 + 1]);
    }
    __syncthreads();

    uint preg[DIM_HID / 2];
#pragma unroll
    for (int kp = 0; kp < DIM_HID / 2; ++kp) preg[kp] = Ph[w][kp][o];

    float qreg = 0.f;
#pragma unroll
    for (int i = 0; i < DIM_IN; ++i) qreg += xs_t[i][w] * b2[i * DIM_OUT + o];

    float2 wcol[BOND];
#pragma unroll
    for (int q = 0; q < BOND; ++q)
        wcol[q] = *(const float2*)(W1 + q * DIM_HID + 2 * o);
    float2 bc = *(const float2*)(b1 + 2 * o);

    EScr* S = (EScr*)&Ph[w][0][0];
    const int n = n0 + w;
    const int start = offsets[n];
    const int deg   = cursor[n] - start;
    const int jj    = o & 15;
    const int prow  = o >> 4;

    for (int gbase = 0; gbase < deg; gbase += 64) {
        const int cnt = (deg - gbase < 64) ? (deg - gbase) : 64;
        __builtin_amdgcn_wave_barrier();
        if (o < cnt) {
            int e = es[start + gbase + o];
            S->eids[o] = e;
            S->dsts[o] = epos[e];  // dst slot position
        }
        __builtin_amdgcn_wave_barrier();
        const int ntiles = (cnt + 7) >> 3;
        float v0, v1;
        {
            int pa = prow, pb = prow + 4;
            bool a0 = (jj < BOND) && (pa < cnt);
            bool a1 = (jj < BOND) && (pb < cnt);
            v0 = a0 ? ea[(long)S->eids[pa] * BOND + jj] : 0.f;
            v1 = a1 ? ea[(long)S->eids[pb] * BOND + jj] : 0.f;
        }
        for (int tb = 0; tb < ntiles; ++tb) {
            __builtin_amdgcn_wave_barrier();
            S->eas[prow][jj]     = v0;
            S->eas[prow + 4][jj] = v1;
            __builtin_amdgcn_wave_barrier();
#pragma unroll
            for (int p = 0; p < 8; ++p) {
                const float4* e4 = (const float4*)S->eas[p];
                float4 ev0 = e4[0], ev1 = e4[1], ev2 = e4[2], ev3 = e4[3];
                float h0 = bc.x, h1 = bc.y;
                float eq[BOND] = {ev0.x, ev0.y, ev0.z, ev0.w,
                                  ev1.x, ev1.y, ev1.z, ev1.w,
                                  ev2.x, ev2.y, ev2.z, ev2.w, ev3.x};
#pragma unroll
                for (int q = 0; q < BOND; ++q) {
                    h0 += eq[q] * wcol[q].x;
                    h1 += eq[q] * wcol[q].y;
                }
                S->hbuf[p][o] = packh2(h0 > 0.f ? h0 : 0.f, h1 > 0.f ? h1 : 0.f);
            }
            if (tb + 1 < ntiles) {
                int pa = (tb + 1) * 8 + prow, pb = pa + 4;
                bool a0 = (jj < BOND) && (pa < cnt);
                bool a1 = (jj < BOND) && (pb < cnt);
                v0 = a0 ? ea[(long)S->eids[pa] * BOND + jj] : 0.f;
                v1 = a1 ? ea[(long)S->eids[pb] * BOND + jj] : 0.f;
            }
            __builtin_amdgcn_wave_barrier();
            const int tcnt = cnt - tb * 8;
#pragma unroll
            for (int p = 0; p < 8; ++p) {
                if (p < tcnt) {
                    const uint4* h4 = (const uint4*)S->hbuf[p];
                    float acc = qreg;
#pragma unroll
                    for (int m = 0; m < 16; ++m) {
                        uint4 hv = h4[m];
                        acc = fdot2u(hv.x, preg[4 * m + 0], acc);
                        acc = fdot2u(hv.y, preg[4 * m + 1], acc);
                        acc = fdot2u(hv.z, preg[4 * m + 2], acc);
                        acc = fdot2u(hv.w, preg[4 * m + 3], acc);
                    }
                    int pos = __builtin_amdgcn_readfirstlane(S->dsts[tb * 8 + p]);
                    msgbuf[(long)pos * DIM_OUT + o] =
                        __builtin_bit_cast(ushort, (_Float16)acc);
                }
            }
        }
    }
}

// phase 2: gather contiguous messages per dst node + root term + relu -> out
__global__ __launch_bounds__(256) void phase2_kernel(
    const float* __restrict__ x, const float* __restrict__ root,
    const float* __restrict__ bias, const int* __restrict__ off_d,
    const int* __restrict__ cur_d, const ushort* __restrict__ msgbuf,
    float* __restrict__ out)
{
    const int t = threadIdx.x;
    const int o = t & 63;
    const int w = t >> 6;
    const int n = blockIdx.x * 4 + w;
    const int start = off_d[n];
    const int end   = cur_d[n];
    float acc = 0.f;
    for (int p = start; p < end; ++p) {
        ushort m = msgbuf[(long)p * DIM_OUT + o];
        acc += (float)__builtin_bit_cast(_Float16, m);
    }
    float r = bias[o];
    const float* xn = x + n * DIM_IN;
#pragma unroll
    for (int i = 0; i < DIM_IN; ++i) r += xn[i] * root[i * DIM_OUT + o];
    float v = acc + r;
    out[n * DIM_OUT + o] = v > 0.f ? v : 0.f;
}

// ======================= atomic fallback path (round-4, proven) =======================

__global__ void prep_kernel(const float* __restrict__ W2, uint* __restrict__ W2p,
                            float* __restrict__ agg, int* __restrict__ counts) {
    int idx = blockIdx.x * 256 + threadIdx.x;
    if (idx < 16 * 64 * DIM_HID) pack_w2(idx, W2, W2p);
    if (idx < N_NODES * DIM_OUT) agg[idx] = 0.f;
    if (idx < N_NODES) counts[idx] = 0;
}

__global__ void hist_kernel(const int* __restrict__ ei, int* __restrict__ counts) {
    int e = blockIdx.x * 256 + threadIdx.x;
    if (e < N_EDGES) atomicAdd(&counts[ei[e]], 1);
}

__global__ void scan_kernel(int* __restrict__ counts, int* __restrict__ cursor) {
    __shared__ int s[1024];
    scan_one(counts, cursor, s);
}

__global__ void scatter_kernel(const int* __restrict__ ei, int* __restrict__ cur,
                               int* __restrict__ es) {
    int e = blockIdx.x * 256 + threadIdx.x;
    if (e < N_EDGES) {
        int pos = atomicAdd(&cur[ei[e]], 1);
        es[pos] = e;
    }
}

__global__ __launch_bounds__(256) void main_kernel(
    const float* __restrict__ x, const int* __restrict__ ei,
    const float* __restrict__ ea, const float* __restrict__ W1,
    const float* __restrict__ b1, const uint* __restrict__ W2p,
    const float* __restrict__ b2, const int* __restrict__ offsets,
    const int* __restrict__ cursor, const int* __restrict__ es,
    float* __restrict__ agg)
{
    __shared__ uint  Ph[NB][DIM_HID / 2][DIM_OUT];
    __shared__ float xs_t[DIM_IN][NB];
    __shared__ uint  xsp[DIM_IN / 2][NB];

    const int t  = threadIdx.x;
    const int o  = t & 63;
    const int w  = t >> 6;
    const int n0 = blockIdx.x * NB;

    if (t < DIM_IN * NB) {
        int i = t >> 2, j = t & 3;
        xs_t[i][j] = x[(n0 + j) * DIM_IN + i];
    }
    __syncthreads();
    if (t < (DIM_IN / 2) * NB) {
        int ip = t >> 2, j = t & 3;
        xsp[ip][j] = packh2(xs_t[2 * ip][j], xs_t[2 * ip + 1][j]);
    }
    __syncthreads();

#pragma unroll
    for (int s = 0; s < 4; ++s) {
        const int kbase = w * 32 + s * 8;
        float acc[NB][8];
#pragma unroll
        for (int j = 0; j < NB; ++j)
#pragma unroll
            for (int q = 0; q < 8; ++q) acc[j][q] = 0.f;
#pragma unroll
        for (int ip = 0; ip < 16; ++ip) {
            const uint4* p4 = (const uint4*)(W2p + (ip * 64 + o) * DIM_HID + kbase);
            uint4 wa = p4[0];
            uint4 wb = p4[1];
            uint xp0 = xsp[ip][0], xp1 = xsp[ip][1];
            uint xp2 = xsp[ip][2], xp3 = xsp[ip][3];
#define DO_NODE(j, xp) \
            acc[j][0] = fdot2u(xp, wa.x, acc[j][0]); \
            acc[j][1] = fdot2u(xp, wa.y, acc[j][1]); \
            acc[j][2] = fdot2u(xp, wa.z, acc[j][2]); \
            acc[j][3] = fdot2u(xp, wa.w, acc[j][3]); \
            acc[j][4] = fdot2u(xp, wb.x, acc[j][4]); \
            acc[j][5] = fdot2u(xp, wb.y, acc[j][5]); \
            acc[j][6] = fdot2u(xp, wb.z, acc[j][6]); \
            acc[j][7] = fdot2u(xp, wb.w, acc[j][7]);
            DO_NODE(0, xp0) DO_NODE(1, xp1) DO_NODE(2, xp2) DO_NODE(3, xp3)
#undef DO_NODE
        }
#pragma unroll
        for (int j = 0; j < NB; ++j)
#pragma unroll
            for (int q2 = 0; q2 < 4; ++q2)
                Ph[j][kbase / 2 + q2][o] = packh2(acc[j][2 * q2], acc[j][2 * q2 + 1]);
    }
    __syncthreads();

    uint preg[DIM_HID / 2];
#pragma unroll
    for (int kp = 0; kp < DIM_HID / 2; ++kp) preg[kp] = Ph[w][kp][o];

    float qreg = 0.f;
#pragma unroll
    for (int i = 0; i < DIM_IN; ++i) qreg += xs_t[i][w] * b2[i * DIM_OUT + o];

    float2 wcol[BOND];
#pragma unroll
    for (int q = 0; q < BOND; ++q)
        wcol[q] = *(const float2*)(W1 + q * DIM_HID + 2 * o);
    float2 bc = *(const float2*)(b1 + 2 * o);

    EScr* S = (EScr*)&Ph[w][0][0];
    const int n = n0 + w;
    const int start = offsets[n];
    const int deg   = cursor[n] - start;
    const int jj    = o & 15;
    const int prow  = o >> 4;

    for (int gbase = 0; gbase < deg; gbase += 64) {
        const int cnt = (deg - gbase < 64) ? (deg - gbase) : 64;
        __builtin_amdgcn_wave_barrier();
        if (o < cnt) {
            int e = es[start + gbase + o];
            S->eids[o] = e;
            S->dsts[o] = ei[N_EDGES + e];
        }
        __builtin_amdgcn_wave_barrier();
        const int ntiles = (cnt + 7) >> 3;
        float v0, v1;
        {
            int pa = prow, pb = prow + 4;
            bool a0 = (jj < BOND) && (pa < cnt);
            bool a1 = (jj < BOND) && (pb < cnt);
            v0 = a0 ? ea[(long)S->eids[pa] * BOND + jj] : 0.f;
            v1 = a1 ? ea[(long)S->eids[pb] * BOND + jj] : 0.f;
        }
        for (int tb = 0; tb < ntiles; ++tb) {
            __builtin_amdgcn_wave_barrier();
            S->eas[prow][jj]     = v0;
            S->eas[prow + 4][jj] = v1;
            __builtin_amdgcn_wave_barrier();
#pragma unroll
            for (int p = 0; p < 8; ++p) {
                const float4* e4 = (const float4*)S->eas[p];
                float4 ev0 = e4[0], ev1 = e4[1], ev2 = e4[2], ev3 = e4[3];
                float h0 = bc.x, h1 = bc.y;
                float eq[BOND] = {ev0.x, ev0.y, ev0.z, ev0.w,
                                  ev1.x, ev1.y, ev1.z, ev1.w,
                                  ev2.x, ev2.y, ev2.z, ev2.w, ev3.x};
#pragma unroll
                for (int q = 0; q < BOND; ++q) {
                    h0 += eq[q] * wcol[q].x;
                    h1 += eq[q] * wcol[q].y;
                }
                S->hbuf[p][o] = packh2(h0 > 0.f ? h0 : 0.f, h1 > 0.f ? h1 : 0.f);
            }
            if (tb + 1 < ntiles) {
                int pa = (tb + 1) * 8 + prow, pb = pa + 4;
                bool a0 = (jj < BOND) && (pa < cnt);
                bool a1 = (jj < BOND) && (pb < cnt);
                v0 = a0 ? ea[(long)S->eids[pa] * BOND + jj] : 0.f;
                v1 = a1 ? ea[(long)S->eids[pb] * BOND + jj] : 0.f;
            }
            __builtin_amdgcn_wave_barrier();
            const int tcnt = cnt - tb * 8;
#pragma unroll
            for (int p = 0; p < 8; ++p) {
                if (p < tcnt) {
                    const uint4* h4 = (const uint4*)S->hbuf[p];
                    float acc = qreg;
#pragma unroll
                    for (int m = 0; m < 16; ++m) {
                        uint4 hv = h4[m];
                        acc = fdot2u(hv.x, preg[4 * m + 0], acc);
                        acc = fdot2u(hv.y, preg[4 * m + 1], acc);
                        acc = fdot2u(hv.z, preg[4 * m + 2], acc);
                        acc = fdot2u(hv.w, preg[4 * m + 3], acc);
                    }
                    int dst = __builtin_amdgcn_readfirstlane(S->dsts[tb * 8 + p]);
                    atomicAdd(&agg[(long)dst * DIM_OUT + o], acc);
                }
            }
        }
    }
}

__global__ void finalize_kernel(const float* __restrict__ x,
                                const float* __restrict__ root,
                                const float* __restrict__ bias,
                                float* __restrict__ out) {
    int idx = blockIdx.x * 256 + threadIdx.x;
    if (idx >= N_NODES * DIM_OUT) return;
    int n = idx >> 6, o = idx & 63;
    float r = bias[o];
    const float* xn = x + n * DIM_IN;
#pragma unroll
    for (int i = 0; i < DIM_IN; ++i) r += xn[i] * root[i * DIM_OUT + o];
    float v = out[idx] + r;
    out[idx] = v > 0.f ? v : 0.f;
}

// ======================= launch =======================

extern "C" void kernel_launch(void* const* d_in, const int* in_sizes, int n_in,
                              void* d_out, int out_size, void* d_ws, size_t ws_size,
                              hipStream_t stream) {
    const float* x    = (const float*)d_in[0];
    const int*   ei   = (const int*)d_in[1];   // [2, E]: row 0 = src, row 1 = dst
    const float* ea   = (const float*)d_in[2];
    const float* W1   = (const float*)d_in[3];
    const float* b1   = (const float*)d_in[4];
    const float* W2   = (const float*)d_in[5];
    const float* b2   = (const float*)d_in[6];
    const float* root = (const float*)d_in[7];
    const float* bias = (const float*)d_in[8];
    float* out = (float*)d_out;
    char* ws = (char*)d_ws;

    // two-phase layout
    const size_t OFF_CSRC = 0;
    const size_t OFF_CURS = 40064;
    const size_t OFF_CDST = 80128;
    const size_t OFF_CURD = 120192;
    const size_t OFF_ES   = 160256;
    const size_t OFF_EPOS = 800256;
    const size_t OFF_W2P  = 1440256;
    const size_t OFF_MSG  = 1964544;
    const size_t NEED_2P  = OFF_MSG + (size_t)N_EDGES * DIM_OUT * 2;  // 22,444,544

    if (ws_size >= NEED_2P) {
        int* csrc   = (int*)(ws + OFF_CSRC);
        int* cur_s  = (int*)(ws + OFF_CURS);
        int* cdst   = (int*)(ws + OFF_CDST);
        int* cur_d  = (int*)(ws + OFF_CURD);
        int* es     = (int*)(ws + OFF_ES);
        int* epos   = (int*)(ws + OFF_EPOS);
        uint* W2p   = (uint*)(ws + OFF_W2P);
        ushort* msg = (ushort*)(ws + OFF_MSG);

        prep2_kernel<<<512, 256, 0, stream>>>(W2, W2p, csrc, cdst);
        hist2_kernel<<<(N_EDGES + 255) / 256, 256, 0, stream>>>(ei, csrc, cdst);
        scan2_kernel<<<1, 1024, 0, stream>>>(csrc, cur_s, cdst, cur_d);
        scatter2_kernel<<<(N_EDGES + 255) / 256, 256, 0, stream>>>(ei, cur_s, cur_d, es, epos);
        phase1_kernel<<<N_NODES / NB, 256, 0, stream>>>(x, ea, W1, b1, W2p, b2,
                                                        csrc, cur_s, es, epos, msg);
        phase2_kernel<<<N_NODES / 4, 256, 0, stream>>>(x, root, bias, cdst, cur_d, msg, out);
    } else {
        // atomic fallback (round-4 layout, ~1.22 MB)
        int*  counts = (int*)(ws);
        int*  cursor = (int*)(ws + 40064);
        int*  es     = (int*)(ws + 80128);
        uint* W2p    = (uint*)(ws + 720384);

        prep_kernel<<<2500, 256, 0, stream>>>(W2, W2p, out, counts);
        hist_kernel<<<(N_EDGES + 255) / 256, 256, 0, stream>>>(ei, counts);
        scan_kernel<<<1, 1024, 0, stream>>>(counts, cursor);
        scatter_kernel<<<(N_EDGES + 255) / 256, 256, 0, stream>>>(ei, cursor, es);
        main_kernel<<<N_NODES / NB, 256, 0, stream>>>(x, ei, ea, W1, b1, W2p, b2,
                                                      counts, cursor, es, out);
        finalize_kernel<<<(N_NODES * DIM_OUT + 255) / 256, 256, 0, stream>>>(x, root, bias, out);
    }
}

// Round 6
// 276.068 us; speedup vs baseline: 1.6810x; 1.6810x over previous
//
#include <hip/hip_runtime.h>

// Problem constants (match reference)
#define N_NODES 10000
#define N_EDGES 160000
#define DIM_IN 32
#define DIM_OUT 64
#define DIM_HID 128
#define BOND 13
#define NB 4  // source nodes per workgroup (one per wave)

typedef _Float16 half2_t __attribute__((ext_vector_type(2)));
typedef unsigned int uint;
typedef unsigned short ushort;

static __device__ __forceinline__ float fdot2u(uint a, uint b, float c) {
#if __has_builtin(__builtin_amdgcn_fdot2)
    return __builtin_amdgcn_fdot2(__builtin_bit_cast(half2_t, a),
                                  __builtin_bit_cast(half2_t, b), c, false);
#else
    half2_t ha = __builtin_bit_cast(half2_t, a);
    half2_t hb = __builtin_bit_cast(half2_t, b);
    return c + (float)ha.x * (float)hb.x + (float)ha.y * (float)hb.y;
#endif
}

static __device__ __forceinline__ uint packh2(float a, float b) {
    half2_t h;
    h.x = (_Float16)a; h.y = (_Float16)b;
    return __builtin_bit_cast(uint, h);
}

// Ph column swizzle: rotate column by k-pair to break the 128-uint write stride
static __device__ __forceinline__ int swz(int o, int kp) { return (o + kp) & 63; }

// ======================= shared helpers =======================

// W2 f32 [k][i*64+o] -> f16x2 i-paired W2p[(ip*64+o)*128 + k]
static __device__ __forceinline__ void pack_w2(int idx, const float* W2, uint* W2p) {
    int ip = idx >> 13;
    int o  = (idx >> 7) & 63;
    int k  = idx & 127;
    float lo = W2[k * 2048 + (2 * ip) * 64 + o];
    float hi = W2[k * 2048 + (2 * ip + 1) * 64 + o];
    W2p[idx] = packh2(lo, hi);
}

// single-block exclusive scan of counts->offsets, duplicate into cursor
static __device__ __forceinline__ void scan_one(int* counts, int* cursor, int* s) {
    const int t = threadIdx.x;
    const int base = t * 10;  // 1024*10 >= 10000
    int loc[10];
    int sum = 0;
#pragma unroll
    for (int u = 0; u < 10; ++u) {
        int idx = base + u;
        int v = (idx < N_NODES) ? counts[idx] : 0;
        loc[u] = v; sum += v;
    }
    s[t] = sum;
    __syncthreads();
    for (int off = 1; off < 1024; off <<= 1) {
        int add = (t >= off) ? s[t - off] : 0;
        __syncthreads();
        s[t] += add;
        __syncthreads();
    }
    int run = s[t] - sum;
#pragma unroll
    for (int u = 0; u < 10; ++u) {
        int idx = base + u;
        if (idx < N_NODES) { counts[idx] = run; cursor[idx] = run; }
        run += loc[u];
    }
}

// per-wave edge scratch, overlaid on this wave's 16 KB Ph slot after preg load
struct EScr {
    int   eids[64];
    int   dsts[64];     // dst node (atomic path) OR dst slot position (2-phase)
    float eas[8][16];   // 16B-aligned rows
    uint  hbuf[8][64];  // 16B aligned for uint4 reads
};

// ======================= two-phase path =======================

__global__ void prep2_kernel(const float* __restrict__ W2, uint* __restrict__ W2p,
                             int* __restrict__ csrc, int* __restrict__ cdst) {
    int idx = blockIdx.x * 256 + threadIdx.x;  // grid 512 blocks -> 131072
    if (idx < 16 * 64 * DIM_HID) pack_w2(idx, W2, W2p);
    if (idx < N_NODES) { csrc[idx] = 0; cdst[idx] = 0; }
}

__global__ void hist2_kernel(const int* __restrict__ ei, int* __restrict__ csrc,
                             int* __restrict__ cdst) {
    int e = blockIdx.x * 256 + threadIdx.x;
    if (e < N_EDGES) {
        atomicAdd(&csrc[ei[e]], 1);
        atomicAdd(&cdst[ei[N_EDGES + e]], 1);
    }
}

__global__ void scan2_kernel(int* __restrict__ csrc, int* __restrict__ cur_s,
                             int* __restrict__ cdst, int* __restrict__ cur_d) {
    __shared__ int s[1024];
    scan_one(csrc, cur_s, s);
    __syncthreads();
    scan_one(cdst, cur_d, s);
}

__global__ void scatter2_kernel(const int* __restrict__ ei, int* __restrict__ cur_s,
                                int* __restrict__ cur_d, int* __restrict__ es,
                                int* __restrict__ epos) {
    int e = blockIdx.x * 256 + threadIdx.x;
    if (e < N_EDGES) {
        int ps = atomicAdd(&cur_s[ei[e]], 1);
        es[ps] = e;
        int pd = atomicAdd(&cur_d[ei[N_EDGES + e]], 1);
        epos[e] = pd;
    }
}

// phase 1: coalesced P build -> register P -> tiled edge phase -> f16 msg store
__global__ __launch_bounds__(256) void phase1_kernel(
    const float* __restrict__ x, const float* __restrict__ ea,
    const float* __restrict__ W1, const float* __restrict__ b1,
    const uint* __restrict__ W2p, const float* __restrict__ b2,
    const int* __restrict__ offsets, const int* __restrict__ cursor,
    const int* __restrict__ es, const int* __restrict__ epos,
    ushort* __restrict__ msgbuf)
{
    __shared__ uint  Ph[NB][DIM_HID / 2][DIM_OUT];  // 64 KiB, reused as EScr later
    __shared__ float xs_t[DIM_IN][NB];
    __shared__ uint  xsp[DIM_IN / 2][NB];

    const int t  = threadIdx.x;
    const int o  = t & 63;    // lane
    const int w  = t >> 6;
    const int n0 = blockIdx.x * NB;
    const int lhi = o >> 5;   // 0/1: which o-row within a load
    const int kq  = o & 31;   // k-quad index (k = 4*kq .. 4*kq+3)

    if (t < DIM_IN * NB) {
        int i = t >> 2, j = t & 3;
        xs_t[i][j] = x[(n0 + j) * DIM_IN + i];
    }
    __syncthreads();
    if (t < (DIM_IN / 2) * NB) {
        int ip = t >> 2, j = t & 3;
        xsp[ip][j] = packh2(xs_t[2 * ip][j], xs_t[2 * ip + 1][j]);
    }
    __syncthreads();

    // ---- P build: lane-CONTIGUOUS W2p loads (1 KB per wave-instr) ----
    // otile ot: block covers o-rows [ot*16, ot*16+16); wave w covers 4 of them.
#pragma unroll
    for (int ot = 0; ot < 4; ++ot) {
        float acc[2][NB][4];
#pragma unroll
        for (int l = 0; l < 2; ++l)
#pragma unroll
            for (int j = 0; j < NB; ++j)
#pragma unroll
                for (int q = 0; q < 4; ++q) acc[l][j][q] = 0.f;
#pragma unroll
        for (int ip = 0; ip < 16; ++ip) {
            const uint4* base4 = (const uint4*)W2p + ((ip * 64 + ot * 16) << 5);
            uint4 wv0 = base4[w * 128 + o];        // o-row = ot*16+w*4+lhi,   k-quad kq
            uint4 wv1 = base4[w * 128 + 64 + o];   // o-row = ot*16+w*4+2+lhi, k-quad kq
            uint xp0 = xsp[ip][0], xp1 = xsp[ip][1];
            uint xp2 = xsp[ip][2], xp3 = xsp[ip][3];
#define ACC4(l, wv, xp, j) \
            acc[l][j][0] = fdot2u(xp, wv.x, acc[l][j][0]); \
            acc[l][j][1] = fdot2u(xp, wv.y, acc[l][j][1]); \
            acc[l][j][2] = fdot2u(xp, wv.z, acc[l][j][2]); \
            acc[l][j][3] = fdot2u(xp, wv.w, acc[l][j][3]);
            ACC4(0, wv0, xp0, 0) ACC4(0, wv0, xp1, 1)
            ACC4(0, wv0, xp2, 2) ACC4(0, wv0, xp3, 3)
            ACC4(1, wv1, xp0, 0) ACC4(1, wv1, xp1, 1)
            ACC4(1, wv1, xp2, 2) ACC4(1, wv1, xp3, 3)
#undef ACC4
        }
        const int o0 = ot * 16 + w * 4 + lhi;  // l=0 output column
        const int o1 = o0 + 2;                 // l=1 output column
        const int kp0 = 2 * kq, kp1 = 2 * kq + 1;
#pragma unroll
        for (int j = 0; j < NB; ++j) {
            Ph[j][kp0][swz(o0, kp0)] = packh2(acc[0][j][0], acc[0][j][1]);
            Ph[j][kp1][swz(o0, kp1)] = packh2(acc[0][j][2], acc[0][j][3]);
            Ph[j][kp0][swz(o1, kp0)] = packh2(acc[1][j][0], acc[1][j][1]);
            Ph[j][kp1][swz(o1, kp1)] = packh2(acc[1][j][2], acc[1][j][3]);
        }
    }
    __syncthreads();

    // ---- node w's P into this wave's registers (unswizzle) ----
    uint preg[DIM_HID / 2];
#pragma unroll
    for (int kp = 0; kp < DIM_HID / 2; ++kp) preg[kp] = Ph[w][kp][swz(o, kp)];

    float qreg = 0.f;
#pragma unroll
    for (int i = 0; i < DIM_IN; ++i) qreg += xs_t[i][w] * b2[i * DIM_OUT + o];

    float2 wcol[BOND];
#pragma unroll
    for (int q = 0; q < BOND; ++q)
        wcol[q] = *(const float2*)(W1 + q * DIM_HID + 2 * o);
    float2 bc = *(const float2*)(b1 + 2 * o);

    EScr* S = (EScr*)&Ph[w][0][0];
    const int n = n0 + w;
    const int start = offsets[n];
    const int deg   = cursor[n] - start;
    const int jj    = o & 15;
    const int prow  = o >> 4;

    __builtin_amdgcn_wave_barrier();
    for (int gbase = 0; gbase < deg; gbase += 64) {
        const int cnt = (deg - gbase < 64) ? (deg - gbase) : 64;
        __builtin_amdgcn_wave_barrier();
        if (o < cnt) {
            int e = es[start + gbase + o];
            S->eids[o] = e;
            S->dsts[o] = epos[e];  // dst slot position
        }
        __builtin_amdgcn_wave_barrier();
        const int ntiles = (cnt + 7) >> 3;
        float v0, v1;
        {
            int pa = prow, pb = prow + 4;
            bool a0 = (jj < BOND) && (pa < cnt);
            bool a1 = (jj < BOND) && (pb < cnt);
            v0 = a0 ? ea[(long)S->eids[pa] * BOND + jj] : 0.f;
            v1 = a1 ? ea[(long)S->eids[pb] * BOND + jj] : 0.f;
        }
        for (int tb = 0; tb < ntiles; ++tb) {
            __builtin_amdgcn_wave_barrier();
            S->eas[prow][jj]     = v0;
            S->eas[prow + 4][jj] = v1;
            __builtin_amdgcn_wave_barrier();
#pragma unroll
            for (int p = 0; p < 8; ++p) {
                const float4* e4 = (const float4*)S->eas[p];
                float4 ev0 = e4[0], ev1 = e4[1], ev2 = e4[2], ev3 = e4[3];
                float h0 = bc.x, h1 = bc.y;
                float eq[BOND] = {ev0.x, ev0.y, ev0.z, ev0.w,
                                  ev1.x, ev1.y, ev1.z, ev1.w,
                                  ev2.x, ev2.y, ev2.z, ev2.w, ev3.x};
#pragma unroll
                for (int q = 0; q < BOND; ++q) {
                    h0 += eq[q] * wcol[q].x;
                    h1 += eq[q] * wcol[q].y;
                }
                S->hbuf[p][o] = packh2(h0 > 0.f ? h0 : 0.f, h1 > 0.f ? h1 : 0.f);
            }
            if (tb + 1 < ntiles) {
                int pa = (tb + 1) * 8 + prow, pb = pa + 4;
                bool a0 = (jj < BOND) && (pa < cnt);
                bool a1 = (jj < BOND) && (pb < cnt);
                v0 = a0 ? ea[(long)S->eids[pa] * BOND + jj] : 0.f;
                v1 = a1 ? ea[(long)S->eids[pb] * BOND + jj] : 0.f;
            }
            __builtin_amdgcn_wave_barrier();
            const int tcnt = cnt - tb * 8;
#pragma unroll
            for (int p = 0; p < 8; ++p) {
                if (p < tcnt) {
                    const uint4* h4 = (const uint4*)S->hbuf[p];
                    float acc = qreg;
#pragma unroll
                    for (int m = 0; m < 16; ++m) {
                        uint4 hv = h4[m];
                        acc = fdot2u(hv.x, preg[4 * m + 0], acc);
                        acc = fdot2u(hv.y, preg[4 * m + 1], acc);
                        acc = fdot2u(hv.z, preg[4 * m + 2], acc);
                        acc = fdot2u(hv.w, preg[4 * m + 3], acc);
                    }
                    int pos = __builtin_amdgcn_readfirstlane(S->dsts[tb * 8 + p]);
                    msgbuf[(long)pos * DIM_OUT + o] =
                        __builtin_bit_cast(ushort, (_Float16)acc);
                }
            }
        }
    }
}

// phase 2: gather contiguous messages per dst node + root term + relu -> out
__global__ __launch_bounds__(256) void phase2_kernel(
    const float* __restrict__ x, const float* __restrict__ root,
    const float* __restrict__ bias, const int* __restrict__ off_d,
    const int* __restrict__ cur_d, const ushort* __restrict__ msgbuf,
    float* __restrict__ out)
{
    const int t = threadIdx.x;
    const int o = t & 63;
    const int w = t >> 6;
    const int n = blockIdx.x * 4 + w;
    const int start = off_d[n];
    const int end   = cur_d[n];
    float acc = 0.f;
    for (int p = start; p < end; ++p) {
        ushort m = msgbuf[(long)p * DIM_OUT + o];
        acc += (float)__builtin_bit_cast(_Float16, m);
    }
    float r = bias[o];
    const float* xn = x + n * DIM_IN;
#pragma unroll
    for (int i = 0; i < DIM_IN; ++i) r += xn[i] * root[i * DIM_OUT + o];
    float v = acc + r;
    out[n * DIM_OUT + o] = v > 0.f ? v : 0.f;
}

// ======================= atomic fallback path (proven round-4 code) =======================

__global__ void prep_kernel(const float* __restrict__ W2, uint* __restrict__ W2p,
                            float* __restrict__ agg, int* __restrict__ counts) {
    int idx = blockIdx.x * 256 + threadIdx.x;
    if (idx < 16 * 64 * DIM_HID) pack_w2(idx, W2, W2p);
    if (idx < N_NODES * DIM_OUT) agg[idx] = 0.f;
    if (idx < N_NODES) counts[idx] = 0;
}

__global__ void hist_kernel(const int* __restrict__ ei, int* __restrict__ counts) {
    int e = blockIdx.x * 256 + threadIdx.x;
    if (e < N_EDGES) atomicAdd(&counts[ei[e]], 1);
}

__global__ void scan_kernel(int* __restrict__ counts, int* __restrict__ cursor) {
    __shared__ int s[1024];
    scan_one(counts, cursor, s);
}

__global__ void scatter_kernel(const int* __restrict__ ei, int* __restrict__ cur,
                               int* __restrict__ es) {
    int e = blockIdx.x * 256 + threadIdx.x;
    if (e < N_EDGES) {
        int pos = atomicAdd(&cur[ei[e]], 1);
        es[pos] = e;
    }
}

__global__ __launch_bounds__(256) void main_kernel(
    const float* __restrict__ x, const int* __restrict__ ei,
    const float* __restrict__ ea, const float* __restrict__ W1,
    const float* __restrict__ b1, const uint* __restrict__ W2p,
    const float* __restrict__ b2, const int* __restrict__ offsets,
    const int* __restrict__ cursor, const int* __restrict__ es,
    float* __restrict__ agg)
{
    __shared__ uint  Ph[NB][DIM_HID / 2][DIM_OUT];
    __shared__ float xs_t[DIM_IN][NB];
    __shared__ uint  xsp[DIM_IN / 2][NB];

    const int t  = threadIdx.x;
    const int o  = t & 63;
    const int w  = t >> 6;
    const int n0 = blockIdx.x * NB;

    if (t < DIM_IN * NB) {
        int i = t >> 2, j = t & 3;
        xs_t[i][j] = x[(n0 + j) * DIM_IN + i];
    }
    __syncthreads();
    if (t < (DIM_IN / 2) * NB) {
        int ip = t >> 2, j = t & 3;
        xsp[ip][j] = packh2(xs_t[2 * ip][j], xs_t[2 * ip + 1][j]);
    }
    __syncthreads();

#pragma unroll
    for (int s = 0; s < 4; ++s) {
        const int kbase = w * 32 + s * 8;
        float acc[NB][8];
#pragma unroll
        for (int j = 0; j < NB; ++j)
#pragma unroll
            for (int q = 0; q < 8; ++q) acc[j][q] = 0.f;
#pragma unroll
        for (int ip = 0; ip < 16; ++ip) {
            const uint4* p4 = (const uint4*)(W2p + (ip * 64 + o) * DIM_HID + kbase);
            uint4 wa = p4[0];
            uint4 wb = p4[1];
            uint xp0 = xsp[ip][0], xp1 = xsp[ip][1];
            uint xp2 = xsp[ip][2], xp3 = xsp[ip][3];
#define DO_NODE(j, xp) \
            acc[j][0] = fdot2u(xp, wa.x, acc[j][0]); \
            acc[j][1] = fdot2u(xp, wa.y, acc[j][1]); \
            acc[j][2] = fdot2u(xp, wa.z, acc[j][2]); \
            acc[j][3] = fdot2u(xp, wa.w, acc[j][3]); \
            acc[j][4] = fdot2u(xp, wb.x, acc[j][4]); \
            acc[j][5] = fdot2u(xp, wb.y, acc[j][5]); \
            acc[j][6] = fdot2u(xp, wb.z, acc[j][6]); \
            acc[j][7] = fdot2u(xp, wb.w, acc[j][7]);
            DO_NODE(0, xp0) DO_NODE(1, xp1) DO_NODE(2, xp2) DO_NODE(3, xp3)
#undef DO_NODE
        }
#pragma unroll
        for (int j = 0; j < NB; ++j)
#pragma unroll
            for (int q2 = 0; q2 < 4; ++q2)
                Ph[j][kbase / 2 + q2][o] = packh2(acc[j][2 * q2], acc[j][2 * q2 + 1]);
    }
    __syncthreads();

    uint preg[DIM_HID / 2];
#pragma unroll
    for (int kp = 0; kp < DIM_HID / 2; ++kp) preg[kp] = Ph[w][kp][o];

    float qreg = 0.f;
#pragma unroll
    for (int i = 0; i < DIM_IN; ++i) qreg += xs_t[i][w] * b2[i * DIM_OUT + o];

    float2 wcol[BOND];
#pragma unroll
    for (int q = 0; q < BOND; ++q)
        wcol[q] = *(const float2*)(W1 + q * DIM_HID + 2 * o);
    float2 bc = *(const float2*)(b1 + 2 * o);

    EScr* S = (EScr*)&Ph[w][0][0];
    const int n = n0 + w;
    const int start = offsets[n];
    const int deg   = cursor[n] - start;
    const int jj    = o & 15;
    const int prow  = o >> 4;

    for (int gbase = 0; gbase < deg; gbase += 64) {
        const int cnt = (deg - gbase < 64) ? (deg - gbase) : 64;
        __builtin_amdgcn_wave_barrier();
        if (o < cnt) {
            int e = es[start + gbase + o];
            S->eids[o] = e;
            S->dsts[o] = ei[N_EDGES + e];
        }
        __builtin_amdgcn_wave_barrier();
        const int ntiles = (cnt + 7) >> 3;
        float v0, v1;
        {
            int pa = prow, pb = prow + 4;
            bool a0 = (jj < BOND) && (pa < cnt);
            bool a1 = (jj < BOND) && (pb < cnt);
            v0 = a0 ? ea[(long)S->eids[pa] * BOND + jj] : 0.f;
            v1 = a1 ? ea[(long)S->eids[pb] * BOND + jj] : 0.f;
        }
        for (int tb = 0; tb < ntiles; ++tb) {
            __builtin_amdgcn_wave_barrier();
            S->eas[prow][jj]     = v0;
            S->eas[prow + 4][jj] = v1;
            __builtin_amdgcn_wave_barrier();
#pragma unroll
            for (int p = 0; p < 8; ++p) {
                const float4* e4 = (const float4*)S->eas[p];
                float4 ev0 = e4[0], ev1 = e4[1], ev2 = e4[2], ev3 = e4[3];
                float h0 = bc.x, h1 = bc.y;
                float eq[BOND] = {ev0.x, ev0.y, ev0.z, ev0.w,
                                  ev1.x, ev1.y, ev1.z, ev1.w,
                                  ev2.x, ev2.y, ev2.z, ev2.w, ev3.x};
#pragma unroll
                for (int q = 0; q < BOND; ++q) {
                    h0 += eq[q] * wcol[q].x;
                    h1 += eq[q] * wcol[q].y;
                }
                S->hbuf[p][o] = packh2(h0 > 0.f ? h0 : 0.f, h1 > 0.f ? h1 : 0.f);
            }
            if (tb + 1 < ntiles) {
                int pa = (tb + 1) * 8 + prow, pb = pa + 4;
                bool a0 = (jj < BOND) && (pa < cnt);
                bool a1 = (jj < BOND) && (pb < cnt);
                v0 = a0 ? ea[(long)S->eids[pa] * BOND + jj] : 0.f;
                v1 = a1 ? ea[(long)S->eids[pb] * BOND + jj] : 0.f;
            }
            __builtin_amdgcn_wave_barrier();
            const int tcnt = cnt - tb * 8;
#pragma unroll
            for (int p = 0; p < 8; ++p) {
                if (p < tcnt) {
                    const uint4* h4 = (const uint4*)S->hbuf[p];
                    float acc = qreg;
#pragma unroll
                    for (int m = 0; m < 16; ++m) {
                        uint4 hv = h4[m];
                        acc = fdot2u(hv.x, preg[4 * m + 0], acc);
                        acc = fdot2u(hv.y, preg[4 * m + 1], acc);
                        acc = fdot2u(hv.z, preg[4 * m + 2], acc);
                        acc = fdot2u(hv.w, preg[4 * m + 3], acc);
                    }
                    int dst = __builtin_amdgcn_readfirstlane(S->dsts[tb * 8 + p]);
                    atomicAdd(&agg[(long)dst * DIM_OUT + o], acc);
                }
            }
        }
    }
}

__global__ void finalize_kernel(const float* __restrict__ x,
                                const float* __restrict__ root,
                                const float* __restrict__ bias,
                                float* __restrict__ out) {
    int idx = blockIdx.x * 256 + threadIdx.x;
    if (idx >= N_NODES * DIM_OUT) return;
    int n = idx >> 6, o = idx & 63;
    float r = bias[o];
    const float* xn = x + n * DIM_IN;
#pragma unroll
    for (int i = 0; i < DIM_IN; ++i) r += xn[i] * root[i * DIM_OUT + o];
    float v = out[idx] + r;
    out[idx] = v > 0.f ? v : 0.f;
}

// ======================= launch =======================

extern "C" void kernel_launch(void* const* d_in, const int* in_sizes, int n_in,
                              void* d_out, int out_size, void* d_ws, size_t ws_size,
                              hipStream_t stream) {
    const float* x    = (const float*)d_in[0];
    const int*   ei   = (const int*)d_in[1];   // [2, E]: row 0 = src, row 1 = dst
    const float* ea   = (const float*)d_in[2];
    const float* W1   = (const float*)d_in[3];
    const float* b1   = (const float*)d_in[4];
    const float* W2   = (const float*)d_in[5];
    const float* b2   = (const float*)d_in[6];
    const float* root = (const float*)d_in[7];
    const float* bias = (const float*)d_in[8];
    float* out = (float*)d_out;
    char* ws = (char*)d_ws;

    // two-phase layout
    const size_t OFF_CSRC = 0;
    const size_t OFF_CURS = 40064;
    const size_t OFF_CDST = 80128;
    const size_t OFF_CURD = 120192;
    const size_t OFF_ES   = 160256;
    const size_t OFF_EPOS = 800256;
    const size_t OFF_W2P  = 1440256;
    const size_t OFF_MSG  = 1964544;
    const size_t NEED_2P  = OFF_MSG + (size_t)N_EDGES * DIM_OUT * 2;  // 22,444,544

    if (ws_size >= NEED_2P) {
        int* csrc   = (int*)(ws + OFF_CSRC);
        int* cur_s  = (int*)(ws + OFF_CURS);
        int* cdst   = (int*)(ws + OFF_CDST);
        int* cur_d  = (int*)(ws + OFF_CURD);
        int* es     = (int*)(ws + OFF_ES);
        int* epos   = (int*)(ws + OFF_EPOS);
        uint* W2p   = (uint*)(ws + OFF_W2P);
        ushort* msg = (ushort*)(ws + OFF_MSG);

        prep2_kernel<<<512, 256, 0, stream>>>(W2, W2p, csrc, cdst);
        hist2_kernel<<<(N_EDGES + 255) / 256, 256, 0, stream>>>(ei, csrc, cdst);
        scan2_kernel<<<1, 1024, 0, stream>>>(csrc, cur_s, cdst, cur_d);
        scatter2_kernel<<<(N_EDGES + 255) / 256, 256, 0, stream>>>(ei, cur_s, cur_d, es, epos);
        phase1_kernel<<<N_NODES / NB, 256, 0, stream>>>(x, ea, W1, b1, W2p, b2,
                                                        csrc, cur_s, es, epos, msg);
        phase2_kernel<<<N_NODES / 4, 256, 0, stream>>>(x, root, bias, cdst, cur_d, msg, out);
    } else {
        // atomic fallback (round-4 layout, ~1.22 MB)
        int*  counts = (int*)(ws);
        int*  cursor = (int*)(ws + 40064);
        int*  es     = (int*)(ws + 80128);
        uint* W2p    = (uint*)(ws + 720384);

        prep_kernel<<<2500, 256, 0, stream>>>(W2, W2p, out, counts);
        hist_kernel<<<(N_EDGES + 255) / 256, 256, 0, stream>>>(ei, counts);
        scan_kernel<<<1, 1024, 0, stream>>>(counts, cursor);
        scatter_kernel<<<(N_EDGES + 255) / 256, 256, 0, stream>>>(ei, cursor, es);
        main_kernel<<<N_NODES / NB, 256, 0, stream>>>(x, ei, ea, W1, b1, W2p, b2,
                                                      counts, cursor, es, out);
        finalize_kernel<<<(N_NODES * DIM_OUT + 255) / 256, 256, 0, stream>>>(x, root, bias, out);
    }
}